// Round 15
// baseline (697.204 us; speedup 1.0000x reference)
//
#include <hip/hip_runtime.h>
#include <stdint.h>

typedef _Float16 f16;
typedef __attribute__((ext_vector_type(8))) _Float16 f16x8;
typedef __attribute__((ext_vector_type(4))) float f32x4;

#define BATCH 8192
#define INF   1024
#define OUTF  1024
#define KTOT  9216
#define NKT   144   /* total K-tiles of 64 */
#define CONV_BLOCKS 4608   /* 1024*1152/256 */

// ---------------------------------------------------------------------------
__device__ __forceinline__ void gload16(const void* g, void* l) {
  __builtin_amdgcn_global_load_lds(
      (const __attribute__((address_space(1))) uint32_t*)g,
      (__attribute__((address_space(3))) uint32_t*)l, 16, 0, 0);
}

// ---------------------------------------------------------------------------
// Fused prep (R12-proven): blocks [0, CONV_BLOCKS) convert W row-major f16;
// the rest build A (silu | spline basis).
// ---------------------------------------------------------------------------
__global__ __launch_bounds__(256) void fused_prep_kernel(
    const float* __restrict__ bw, const float* __restrict__ sw,
    const float* __restrict__ x, const float* __restrict__ grid,
    f16* __restrict__ Wb, f16* __restrict__ Abuf)
{
  int blk = blockIdx.x;
  if (blk < CONV_BLOCKS) {
    int idx = blk * 256 + threadIdx.x;   // [0, 1024*1152)
    int o = idx / 1152;
    int r = idx - o * 1152;
    int k8 = r * 8;
    const float* src = (k8 < INF) ? (bw + (size_t)o * INF + k8)
                                  : (sw + (size_t)o * (INF * 8) + (k8 - INF));
    float4 v0 = *(const float4*)src;
    float4 v1 = *(const float4*)(src + 4);
    f16x8 ov;
    ov[0] = (f16)v0.x; ov[1] = (f16)v0.y; ov[2] = (f16)v0.z; ov[3] = (f16)v0.w;
    ov[4] = (f16)v1.x; ov[5] = (f16)v1.y; ov[6] = (f16)v1.z; ov[7] = (f16)v1.w;
    *(f16x8*)(Wb + (size_t)o * KTOT + k8) = ov;
    return;
  }

  int q = (blk - CONV_BLOCKS) * 256 + threadIdx.x;   // one thread per 4 (b,i)
  int b = q >> 8;
  int i0 = (q & 255) << 2;
  float4 xv = *(const float4*)(x + ((size_t)b << 10) + i0);
  float xa[4] = {xv.x, xv.y, xv.z, xv.w};

  float g[12];
#pragma unroll
  for (int j = 0; j < 12; ++j) g[j] = grid[j];
  float H  = g[1] - g[0];
  float r1 = 1.0f / H;
  float r2 = 0.5f * r1;
  float r3 = (1.0f / 3.0f) * r1;

  f16 sil[4];
  f16x8 bas[4];
#pragma unroll
  for (int e = 0; e < 4; ++e) {
    float v = xa[e];
    sil[e] = (f16)(v / (1.0f + __expf(-v)));
    float xe = fminf(fmaxf(v, -0.99f), 0.99f);
    float Bv[11];
#pragma unroll
    for (int j = 0; j < 11; ++j) Bv[j] = (xe >= g[j] && xe < g[j + 1]) ? 1.0f : 0.0f;
#pragma unroll
    for (int j = 0; j < 10; ++j) Bv[j] = (xe - g[j]) * r1 * Bv[j] + (g[j + 2] - xe) * r1 * Bv[j + 1];
#pragma unroll
    for (int j = 0; j < 9; ++j)  Bv[j] = (xe - g[j]) * r2 * Bv[j] + (g[j + 3] - xe) * r2 * Bv[j + 1];
#pragma unroll
    for (int j = 0; j < 8; ++j)  Bv[j] = (xe - g[j]) * r3 * Bv[j] + (g[j + 4] - xe) * r3 * Bv[j + 1];
#pragma unroll
    for (int n = 0; n < 8; ++n) bas[e][n] = (f16)Bv[n];
  }
  f16* row = Abuf + (size_t)b * KTOT;
  *(uint64_t*)(row + i0) = *(const uint64_t*)sil;
  f16* bp = row + INF + (size_t)i0 * 8;
#pragma unroll
  for (int e = 0; e < 4; ++e) *(f16x8*)(bp + e * 8) = bas[e];
}

// ---------------------------------------------------------------------------
// GEMM (R12-proven body): C = A * W^T, split-K = NSPLIT.
// 128x256 tile, BK=64, 4 waves (1M x 4N), 16x16x32 MFMA, single-buffered
// 48 KB LDS -> NSPLIT co-resident blocks/CU. Per-tile ledger (unchanged):
//   vmcnt(0) | SBAR | {24 ds_reads weaved with 32 MFMA} | lgkm0 | SBAR |
//   stage(t+1) | 32 register-only MFMA
// L2-locality XCD swizzle; chunk-XOR swizzle (0 conflicts).
// ---------------------------------------------------------------------------
#define LDA(base, m, s) (*(const f16x8*)((base) + (((m)*16 + la) * 64 + ((((s)*4 + lb) ^ lasw) * 8))))
#define LDB(base, n, s) (*(const f16x8*)((base) + ((wcn*64 + (n)*16 + la) * 64 + ((((s)*4 + lb) ^ lasw) * 8))))

#define MFMA1(m, n, s) acc[m][n] = __builtin_amdgcn_mfma_f32_16x16x32_f16(af[m][s], bf[n][s], acc[m][n], 0, 0, 0)
#define MFMA_S0(m0) do { \
  MFMA1(m0,0,0);   MFMA1(m0,1,0);   MFMA1(m0,2,0);   MFMA1(m0,3,0); \
  MFMA1(m0+1,0,0); MFMA1(m0+1,1,0); MFMA1(m0+1,2,0); MFMA1(m0+1,3,0); } while (0)
#define MFMA_S1(m0) do { \
  MFMA1(m0,0,1);   MFMA1(m0,1,1);   MFMA1(m0,2,1);   MFMA1(m0,3,1); \
  MFMA1(m0+1,0,1); MFMA1(m0+1,1,1); MFMA1(m0+1,2,1); MFMA1(m0+1,3,1); } while (0)

#define SCHED0 __builtin_amdgcn_sched_barrier(0)
#define SBARF  do { SCHED0; __builtin_amdgcn_s_barrier(); SCHED0; } while (0)
#define LGKM0  do { asm volatile("s_waitcnt lgkmcnt(0)" ::: "memory"); SCHED0; } while (0)

template <int NSPLIT, bool ATOMIC>
__global__ __launch_bounds__(256, NSPLIT) void kan_gemm_kernel(
    const f16* __restrict__ A, const f16* __restrict__ W,
    float* __restrict__ C, float* __restrict__ P1, float* __restrict__ P2)
{
  __shared__ __align__(16) f16 lsA[128 * 64];   // 16 KB (single buffer)
  __shared__ __align__(16) f16 lsB[256 * 64];   // 32 KB

  const int NTILES = NKT / NSPLIT;
  const size_t K = KTOT;
  // L2-locality swizzle: wgs sharing an A-panel (same tm,split) on ONE XCD.
  int bid = blockIdx.x;                    // 0 .. 64*4*NSPLIT-1
  int xcd = bid & 7;
  int u   = bid >> 3;
  int tm  = xcd * 8 + (u & 7);             // 64 M-tiles of 128 rows
  int tn  = (u >> 3) & 3;
  int split = u >> 5;                      // 0..NSPLIT-1
  size_t kbase = (size_t)split * NTILES * 64;

  int tid = threadIdx.x;
  int w = tid >> 6, l = tid & 63;          // 4 waves
  int wcn = w;                             // wave -> 128x64 output block (n)
  int la = l & 15, lb = l >> 4, lasw = la & 7;

  // staging addressing (pre-swizzled source chunk; linear LDS dest).
  int rh = tid >> 3;                       // row-in-line (0..31)
  int sc = (tid & 7) ^ (rh & 7);
  const f16* aSrc0 = A + (size_t)(tm * 128 + rh) * K + kbase + sc * 8;
  const f16* bSrc0 = W + (size_t)(tn * 256 + rh) * K + kbase + sc * 8;

  auto stageA = [&](int t) {               // A tile 16 KB = 4 lines
    size_t koff = (size_t)t * 64;
#pragma unroll
    for (int ln = 0; ln < 4; ++ln)
      gload16(aSrc0 + (size_t)ln * 32 * K + koff, lsA + ln * 2048 + w * 512);
  };
  auto stageB = [&](int t) {               // B tile 32 KB = 8 lines
    size_t koff = (size_t)t * 64;
#pragma unroll
    for (int ln = 0; ln < 8; ++ln)
      gload16(bSrc0 + (size_t)ln * 32 * K + koff, lsB + ln * 2048 + w * 512);
  };

  f16x8 af[8][2], bf[4][2];
  f32x4 acc[8][4] = {};

  // ---- prologue: stage tile 0
  stageA(0); stageB(0);

  for (int t = 0; t < NTILES; ++t) {
    asm volatile("s_waitcnt vmcnt(0)" ::: "memory");
    SBARF;                                 // buf(t) published by all waves

    // ---- front region: 24 ds_reads weaved with 32 MFMA ----
    bf[0][0] = LDB(lsB, 0, 0); bf[1][0] = LDB(lsB, 1, 0);
    bf[2][0] = LDB(lsB, 2, 0); bf[3][0] = LDB(lsB, 3, 0);
    bf[0][1] = LDB(lsB, 0, 1); bf[1][1] = LDB(lsB, 1, 1);
    bf[2][1] = LDB(lsB, 2, 1); bf[3][1] = LDB(lsB, 3, 1);
    af[0][0] = LDA(lsA, 0, 0); af[0][1] = LDA(lsA, 0, 1);
    af[1][0] = LDA(lsA, 1, 0); af[1][1] = LDA(lsA, 1, 1);
    __builtin_amdgcn_s_setprio(1);
    af[2][0] = LDA(lsA, 2, 0); af[3][0] = LDA(lsA, 3, 0);
    MFMA_S0(0);
    af[2][1] = LDA(lsA, 2, 1); af[3][1] = LDA(lsA, 3, 1);
    MFMA_S1(0);
    af[4][0] = LDA(lsA, 4, 0); af[5][0] = LDA(lsA, 5, 0);
    af[4][1] = LDA(lsA, 4, 1); af[5][1] = LDA(lsA, 5, 1);
    MFMA_S0(2);
    af[6][0] = LDA(lsA, 6, 0); af[7][0] = LDA(lsA, 7, 0);
    af[6][1] = LDA(lsA, 6, 1); af[7][1] = LDA(lsA, 7, 1);
    MFMA_S1(2);
    __builtin_amdgcn_s_setprio(0);

    // all 24 reads RETURNED (LDS sampled) before crossing the barrier
    LGKM0;
    SBARF;

    // ---- overwrite buf with tile t+1; cover latency with reg-only MFMAs
    if (t < NTILES - 1) { stageA(t + 1); stageB(t + 1); }
    __builtin_amdgcn_s_setprio(1);
    MFMA_S0(4); MFMA_S1(4);
    MFMA_S0(6); MFMA_S1(6);
    __builtin_amdgcn_s_setprio(0);
  }

  // ---- epilogue ----
  int rowBase = tm * 128 + lb * 4;
  int colBase = tn * 256 + wcn * 64 + la;
  float* dst = ATOMIC ? C : (split == 0 ? C : (split == 1 ? P1 : P2));
#pragma unroll
  for (int m = 0; m < 8; ++m)
#pragma unroll
    for (int n = 0; n < 4; ++n) {
      int col = colBase + n * 16;
#pragma unroll
      for (int j = 0; j < 4; ++j) {
        int row = rowBase + m * 16 + j;
        if (ATOMIC) atomicAdd(&C[(size_t)row * OUTF + col], acc[m][n][j]);
        else        dst[(size_t)row * OUTF + col] = acc[m][n][j];
      }
    }
}

// ---------------------------------------------------------------------------
__global__ __launch_bounds__(256) void reduce2_kernel(
    float* __restrict__ out, const float* __restrict__ p)
{
  size_t i = ((size_t)blockIdx.x * 256 + threadIdx.x) * 4;
  f32x4 a = *(f32x4*)(out + i);
  f32x4 b = *(const f32x4*)(p + i);
  a += b;
  *(f32x4*)(out + i) = a;
}

__global__ __launch_bounds__(256) void reduce3_kernel(
    float* __restrict__ out, const float* __restrict__ p1,
    const float* __restrict__ p2)
{
  size_t i = ((size_t)blockIdx.x * 256 + threadIdx.x) * 4;
  f32x4 a = *(f32x4*)(out + i);
  f32x4 b = *(const f32x4*)(p1 + i);
  f32x4 c = *(const f32x4*)(p2 + i);
  a += b; a += c;
  *(f32x4*)(out + i) = a;
}

// ---------------------------------------------------------------------------
extern "C" void kernel_launch(void* const* d_in, const int* in_sizes, int n_in,
                              void* d_out, int out_size, void* d_ws, size_t ws_size,
                              hipStream_t stream)
{
  const float* x  = (const float*)d_in[0];
  const float* bw = (const float*)d_in[1];
  const float* sw = (const float*)d_in[2];
  const float* gr = (const float*)d_in[3];
  float* out = (float*)d_out;

  f16* Wb = (f16*)d_ws;
  size_t wBytes = (size_t)OUTF * KTOT * sizeof(f16);      // 18.9 MB
  f16* Abuf = (f16*)((char*)d_ws + wBytes);               // 151 MB
  size_t aBytes = (size_t)BATCH * KTOT * sizeof(f16);
  size_t oBytes = (size_t)BATCH * OUTF * sizeof(float);   // 33.5 MB

  int prepBlocks = (BATCH * INF / 4) / 256;               // 8192
  fused_prep_kernel<<<CONV_BLOCKS + prepBlocks, 256, 0, stream>>>(
      bw, sw, x, gr, Wb, Abuf);

  int rblocks = (int)(oBytes / sizeof(float) / 4 / 256);  // 8192
  if (ws_size >= wBytes + aBytes + 2 * oBytes) {
    // 3-way split-K -> 768 wgs = 3 blocks/CU co-resident
    float* P1 = (float*)((char*)d_ws + wBytes + aBytes);
    float* P2 = P1 + oBytes / sizeof(float);
    kan_gemm_kernel<3, false><<<768, 256, 0, stream>>>(Abuf, Wb, out, P1, P2);
    reduce3_kernel<<<rblocks, 256, 0, stream>>>(out, P1, P2);
  } else if (ws_size >= wBytes + aBytes + oBytes) {
    // R12 champion path: 2-way split-K, 512 wgs = 2 blocks/CU
    float* P1 = (float*)((char*)d_ws + wBytes + aBytes);
    kan_gemm_kernel<2, false><<<512, 256, 0, stream>>>(Abuf, Wb, out, P1, nullptr);
    reduce2_kernel<<<rblocks, 256, 0, stream>>>(out, P1);
  } else {
    hipMemsetAsync(d_out, 0, oBytes, stream);
    kan_gemm_kernel<2, true><<<512, 256, 0, stream>>>(Abuf, Wb, out, nullptr, nullptr);
  }
}

// Round 16
// 244.207 us; speedup vs baseline: 2.8550x; 2.8550x over previous
//
#include <hip/hip_runtime.h>
#include <stdint.h>

typedef _Float16 f16;
typedef __attribute__((ext_vector_type(8))) _Float16 f16x8;
typedef __attribute__((ext_vector_type(4))) float f32x4;

#define BATCH 8192
#define INF   1024
#define OUTF  1024
#define KTOT  9216
#define NKT   144   /* total K-tiles of 64 */
#define CONV_BLOCKS 4608   /* 1024*1152/256 */

// ---------------------------------------------------------------------------
__device__ __forceinline__ void gload16(const void* g, void* l) {
  __builtin_amdgcn_global_load_lds(
      (const __attribute__((address_space(1))) uint32_t*)g,
      (__attribute__((address_space(3))) uint32_t*)l, 16, 0, 0);
}

// ---------------------------------------------------------------------------
// Fused prep (R12-proven): blocks [0, CONV_BLOCKS) convert W row-major f16;
// the rest build A (silu | spline basis).
// ---------------------------------------------------------------------------
__global__ __launch_bounds__(256) void fused_prep_kernel(
    const float* __restrict__ bw, const float* __restrict__ sw,
    const float* __restrict__ x, const float* __restrict__ grid,
    f16* __restrict__ Wb, f16* __restrict__ Abuf)
{
  int blk = blockIdx.x;
  if (blk < CONV_BLOCKS) {
    int idx = blk * 256 + threadIdx.x;   // [0, 1024*1152)
    int o = idx / 1152;
    int r = idx - o * 1152;
    int k8 = r * 8;
    const float* src = (k8 < INF) ? (bw + (size_t)o * INF + k8)
                                  : (sw + (size_t)o * (INF * 8) + (k8 - INF));
    float4 v0 = *(const float4*)src;
    float4 v1 = *(const float4*)(src + 4);
    f16x8 ov;
    ov[0] = (f16)v0.x; ov[1] = (f16)v0.y; ov[2] = (f16)v0.z; ov[3] = (f16)v0.w;
    ov[4] = (f16)v1.x; ov[5] = (f16)v1.y; ov[6] = (f16)v1.z; ov[7] = (f16)v1.w;
    *(f16x8*)(Wb + (size_t)o * KTOT + k8) = ov;
    return;
  }

  int q = (blk - CONV_BLOCKS) * 256 + threadIdx.x;   // one thread per 4 (b,i)
  int b = q >> 8;
  int i0 = (q & 255) << 2;
  float4 xv = *(const float4*)(x + ((size_t)b << 10) + i0);
  float xa[4] = {xv.x, xv.y, xv.z, xv.w};

  float g[12];
#pragma unroll
  for (int j = 0; j < 12; ++j) g[j] = grid[j];
  float H  = g[1] - g[0];
  float r1 = 1.0f / H;
  float r2 = 0.5f * r1;
  float r3 = (1.0f / 3.0f) * r1;

  f16 sil[4];
  f16x8 bas[4];
#pragma unroll
  for (int e = 0; e < 4; ++e) {
    float v = xa[e];
    sil[e] = (f16)(v / (1.0f + __expf(-v)));
    float xe = fminf(fmaxf(v, -0.99f), 0.99f);
    float Bv[11];
#pragma unroll
    for (int j = 0; j < 11; ++j) Bv[j] = (xe >= g[j] && xe < g[j + 1]) ? 1.0f : 0.0f;
#pragma unroll
    for (int j = 0; j < 10; ++j) Bv[j] = (xe - g[j]) * r1 * Bv[j] + (g[j + 2] - xe) * r1 * Bv[j + 1];
#pragma unroll
    for (int j = 0; j < 9; ++j)  Bv[j] = (xe - g[j]) * r2 * Bv[j] + (g[j + 3] - xe) * r2 * Bv[j + 1];
#pragma unroll
    for (int j = 0; j < 8; ++j)  Bv[j] = (xe - g[j]) * r3 * Bv[j] + (g[j + 4] - xe) * r3 * Bv[j + 1];
#pragma unroll
    for (int n = 0; n < 8; ++n) bas[e][n] = (f16)Bv[n];
  }
  f16* row = Abuf + (size_t)b * KTOT;
  *(uint64_t*)(row + i0) = *(const uint64_t*)sil;
  f16* bp = row + INF + (size_t)i0 * 8;
#pragma unroll
  for (int e = 0; e < 4; ++e) *(f16x8*)(bp + e * 8) = bas[e];
}

// ---------------------------------------------------------------------------
// GEMM (R12-proven body): C = A * W^T, split-K = NSPLIT.
// 128x256 tile, BK=64, 4 waves (1M x 4N), 16x16x32 MFMA, single-buffered
// 48 KB LDS -> up to 3 co-resident blocks/CU (LDS-limited; VGPR ~112 allows
// 16 waves/CU). launch_bounds kept at (256,2) so the allocator does NOT
// shrink registers (R15's (256,3) caused 84-VGPR spills, 2.7 GB scratch).
// Per-tile ledger (unchanged):
//   vmcnt(0) | SBAR | {24 ds_reads weaved with 32 MFMA} | lgkm0 | SBAR |
//   stage(t+1) | 32 register-only MFMA
// L2-locality XCD swizzle; chunk-XOR swizzle (0 conflicts).
// ---------------------------------------------------------------------------
#define LDA(base, m, s) (*(const f16x8*)((base) + (((m)*16 + la) * 64 + ((((s)*4 + lb) ^ lasw) * 8))))
#define LDB(base, n, s) (*(const f16x8*)((base) + ((wcn*64 + (n)*16 + la) * 64 + ((((s)*4 + lb) ^ lasw) * 8))))

#define MFMA1(m, n, s) acc[m][n] = __builtin_amdgcn_mfma_f32_16x16x32_f16(af[m][s], bf[n][s], acc[m][n], 0, 0, 0)
#define MFMA_S0(m0) do { \
  MFMA1(m0,0,0);   MFMA1(m0,1,0);   MFMA1(m0,2,0);   MFMA1(m0,3,0); \
  MFMA1(m0+1,0,0); MFMA1(m0+1,1,0); MFMA1(m0+1,2,0); MFMA1(m0+1,3,0); } while (0)
#define MFMA_S1(m0) do { \
  MFMA1(m0,0,1);   MFMA1(m0,1,1);   MFMA1(m0,2,1);   MFMA1(m0,3,1); \
  MFMA1(m0+1,0,1); MFMA1(m0+1,1,1); MFMA1(m0+1,2,1); MFMA1(m0+1,3,1); } while (0)

#define SCHED0 __builtin_amdgcn_sched_barrier(0)
#define SBARF  do { SCHED0; __builtin_amdgcn_s_barrier(); SCHED0; } while (0)
#define LGKM0  do { asm volatile("s_waitcnt lgkmcnt(0)" ::: "memory"); SCHED0; } while (0)

template <int NSPLIT, bool ATOMIC>
__global__ __launch_bounds__(256, 2) void kan_gemm_kernel(
    const f16* __restrict__ A, const f16* __restrict__ W,
    float* __restrict__ C, float* __restrict__ P1, float* __restrict__ P2)
{
  __shared__ __align__(16) f16 lsA[128 * 64];   // 16 KB (single buffer)
  __shared__ __align__(16) f16 lsB[256 * 64];   // 32 KB

  const int NTILES = NKT / NSPLIT;
  const size_t K = KTOT;
  // L2-locality swizzle: wgs sharing an A-panel (same tm,split) on ONE XCD.
  int bid = blockIdx.x;                    // 0 .. 64*4*NSPLIT-1
  int xcd = bid & 7;
  int u   = bid >> 3;
  int tm  = xcd * 8 + (u & 7);             // 64 M-tiles of 128 rows
  int tn  = (u >> 3) & 3;
  int split = u >> 5;                      // 0..NSPLIT-1
  size_t kbase = (size_t)split * NTILES * 64;

  int tid = threadIdx.x;
  int w = tid >> 6, l = tid & 63;          // 4 waves
  int wcn = w;                             // wave -> 128x64 output block (n)
  int la = l & 15, lb = l >> 4, lasw = la & 7;

  // staging addressing (pre-swizzled source chunk; linear LDS dest).
  int rh = tid >> 3;                       // row-in-line (0..31)
  int sc = (tid & 7) ^ (rh & 7);
  const f16* aSrc0 = A + (size_t)(tm * 128 + rh) * K + kbase + sc * 8;
  const f16* bSrc0 = W + (size_t)(tn * 256 + rh) * K + kbase + sc * 8;

  auto stageA = [&](int t) {               // A tile 16 KB = 4 lines
    size_t koff = (size_t)t * 64;
#pragma unroll
    for (int ln = 0; ln < 4; ++ln)
      gload16(aSrc0 + (size_t)ln * 32 * K + koff, lsA + ln * 2048 + w * 512);
  };
  auto stageB = [&](int t) {               // B tile 32 KB = 8 lines
    size_t koff = (size_t)t * 64;
#pragma unroll
    for (int ln = 0; ln < 8; ++ln)
      gload16(bSrc0 + (size_t)ln * 32 * K + koff, lsB + ln * 2048 + w * 512);
  };

  f16x8 af[8][2], bf[4][2];
  f32x4 acc[8][4] = {};

  // ---- prologue: stage tile 0
  stageA(0); stageB(0);

  for (int t = 0; t < NTILES; ++t) {
    asm volatile("s_waitcnt vmcnt(0)" ::: "memory");
    SBARF;                                 // buf(t) published by all waves

    // ---- front region: 24 ds_reads weaved with 32 MFMA ----
    bf[0][0] = LDB(lsB, 0, 0); bf[1][0] = LDB(lsB, 1, 0);
    bf[2][0] = LDB(lsB, 2, 0); bf[3][0] = LDB(lsB, 3, 0);
    bf[0][1] = LDB(lsB, 0, 1); bf[1][1] = LDB(lsB, 1, 1);
    bf[2][1] = LDB(lsB, 2, 1); bf[3][1] = LDB(lsB, 3, 1);
    af[0][0] = LDA(lsA, 0, 0); af[0][1] = LDA(lsA, 0, 1);
    af[1][0] = LDA(lsA, 1, 0); af[1][1] = LDA(lsA, 1, 1);
    __builtin_amdgcn_s_setprio(1);
    af[2][0] = LDA(lsA, 2, 0); af[3][0] = LDA(lsA, 3, 0);
    MFMA_S0(0);
    af[2][1] = LDA(lsA, 2, 1); af[3][1] = LDA(lsA, 3, 1);
    MFMA_S1(0);
    af[4][0] = LDA(lsA, 4, 0); af[5][0] = LDA(lsA, 5, 0);
    af[4][1] = LDA(lsA, 4, 1); af[5][1] = LDA(lsA, 5, 1);
    MFMA_S0(2);
    af[6][0] = LDA(lsA, 6, 0); af[7][0] = LDA(lsA, 7, 0);
    af[6][1] = LDA(lsA, 6, 1); af[7][1] = LDA(lsA, 7, 1);
    MFMA_S1(2);
    __builtin_amdgcn_s_setprio(0);

    // all 24 reads RETURNED (LDS sampled) before crossing the barrier
    LGKM0;
    SBARF;

    // ---- overwrite buf with tile t+1; cover latency with reg-only MFMAs
    if (t < NTILES - 1) { stageA(t + 1); stageB(t + 1); }
    __builtin_amdgcn_s_setprio(1);
    MFMA_S0(4); MFMA_S1(4);
    MFMA_S0(6); MFMA_S1(6);
    __builtin_amdgcn_s_setprio(0);
  }

  // ---- epilogue ----
  int rowBase = tm * 128 + lb * 4;
  int colBase = tn * 256 + wcn * 64 + la;
  float* dst = ATOMIC ? C : (split == 0 ? C : (split == 1 ? P1 : P2));
#pragma unroll
  for (int m = 0; m < 8; ++m)
#pragma unroll
    for (int n = 0; n < 4; ++n) {
      int col = colBase + n * 16;
#pragma unroll
      for (int j = 0; j < 4; ++j) {
        int row = rowBase + m * 16 + j;
        if (ATOMIC) atomicAdd(&C[(size_t)row * OUTF + col], acc[m][n][j]);
        else        dst[(size_t)row * OUTF + col] = acc[m][n][j];
      }
    }
}

// ---------------------------------------------------------------------------
__global__ __launch_bounds__(256) void reduce2_kernel(
    float* __restrict__ out, const float* __restrict__ p)
{
  size_t i = ((size_t)blockIdx.x * 256 + threadIdx.x) * 4;
  f32x4 a = *(f32x4*)(out + i);
  f32x4 b = *(const f32x4*)(p + i);
  a += b;
  *(f32x4*)(out + i) = a;
}

__global__ __launch_bounds__(256) void reduce3_kernel(
    float* __restrict__ out, const float* __restrict__ p1,
    const float* __restrict__ p2)
{
  size_t i = ((size_t)blockIdx.x * 256 + threadIdx.x) * 4;
  f32x4 a = *(f32x4*)(out + i);
  f32x4 b = *(const f32x4*)(p1 + i);
  f32x4 c = *(const f32x4*)(p2 + i);
  a += b; a += c;
  *(f32x4*)(out + i) = a;
}

// ---------------------------------------------------------------------------
extern "C" void kernel_launch(void* const* d_in, const int* in_sizes, int n_in,
                              void* d_out, int out_size, void* d_ws, size_t ws_size,
                              hipStream_t stream)
{
  const float* x  = (const float*)d_in[0];
  const float* bw = (const float*)d_in[1];
  const float* sw = (const float*)d_in[2];
  const float* gr = (const float*)d_in[3];
  float* out = (float*)d_out;

  f16* Wb = (f16*)d_ws;
  size_t wBytes = (size_t)OUTF * KTOT * sizeof(f16);      // 18.9 MB
  f16* Abuf = (f16*)((char*)d_ws + wBytes);               // 151 MB
  size_t aBytes = (size_t)BATCH * KTOT * sizeof(f16);
  size_t oBytes = (size_t)BATCH * OUTF * sizeof(float);   // 33.5 MB

  int prepBlocks = (BATCH * INF / 4) / 256;               // 8192
  fused_prep_kernel<<<CONV_BLOCKS + prepBlocks, 256, 0, stream>>>(
      bw, sw, x, gr, Wb, Abuf);

  int rblocks = (int)(oBytes / sizeof(float) / 4 / 256);  // 8192
  if (ws_size >= wBytes + aBytes + 2 * oBytes) {
    // 3-way split-K -> 768 wgs = 3 blocks/CU co-resident (LDS-limited)
    float* P1 = (float*)((char*)d_ws + wBytes + aBytes);
    float* P2 = P1 + oBytes / sizeof(float);
    kan_gemm_kernel<3, false><<<768, 256, 0, stream>>>(Abuf, Wb, out, P1, P2);
    reduce3_kernel<<<rblocks, 256, 0, stream>>>(out, P1, P2);
  } else if (ws_size >= wBytes + aBytes + oBytes) {
    // R12 champion path: 2-way split-K, 512 wgs = 2 blocks/CU
    float* P1 = (float*)((char*)d_ws + wBytes + aBytes);
    kan_gemm_kernel<2, false><<<512, 256, 0, stream>>>(Abuf, Wb, out, P1, nullptr);
    reduce2_kernel<<<rblocks, 256, 0, stream>>>(out, P1);
  } else {
    hipMemsetAsync(d_out, 0, oBytes, stream);
    kan_gemm_kernel<2, true><<<512, 256, 0, stream>>>(Abuf, Wb, out, nullptr, nullptr);
  }
}